// Round 1
// baseline (437.306 us; speedup 1.0000x reference)
//
#include <hip/hip_runtime.h>
#include <hip/hip_bf16.h>

typedef __bf16 bf16x8 __attribute__((ext_vector_type(8)));
typedef __bf16 bf16x4 __attribute__((ext_vector_type(4)));
typedef float  f32x4  __attribute__((ext_vector_type(4)));

#define N_ROWS 32768
#define D_DIM  256
#define K_PROT 2048

// ws layout (float offsets)
#define WS_Z2    0
#define WS_INVN  32768
#define WS_P2    65536
#define WS_RMIN  67584
#define WS_CMIN  100352
#define WS_ZB    102400   // bf16 Z copy: 32768*256 bf16 = 16 MB (byte off 409600, 16B-aligned)
#define WS_PB    (102400 + 4194304)  // bf16 P copy: 2048*256 bf16 = 1 MB

// out layout (float offsets)
#define OUT_X0   0UL
#define OUT_X1   8388608UL
#define OUT_XMAP 16777216UL
#define OUT_CVAE 83886080UL
#define OUT_PROT 83886081UL

__device__ __forceinline__ void gload16(const __bf16* gsrc, const __bf16* ldst) {
    auto g = (const __attribute__((address_space(1))) unsigned int*)(unsigned long long)gsrc;
    auto l = (__attribute__((address_space(3))) unsigned int*)(unsigned long long)ldst;
    __builtin_amdgcn_global_load_lds(g, l, 16, 0, 0);
}

// ---------------- K12: fused row prep for Z (norms, copies, bf16) and P (norms, bf16) ----------------
__global__ __launch_bounds__(256) void k12_rows(
    const float* __restrict__ Z, const float* __restrict__ P,
    float* __restrict__ out0, float* __restrict__ out1,
    float* __restrict__ z2, float* __restrict__ invn, unsigned int* __restrict__ rmin,
    __bf16* __restrict__ Zb,
    float* __restrict__ p2, unsigned int* __restrict__ cmin, __bf16* __restrict__ Pb)
{
    int b    = blockIdx.x;
    int lane = threadIdx.x & 63;
    if (b < (N_ROWS/4)) {
        int row  = (b << 2) + (threadIdx.x >> 6);
        size_t base = (size_t)row * D_DIM;
        float4 v = ((const float4*)(Z + base))[lane];
        float ss = v.x*v.x + v.y*v.y + v.z*v.z + v.w*v.w;
        #pragma unroll
        for (int d = 32; d >= 1; d >>= 1) ss += __shfl_xor(ss, d);
        float inv = 1.0f / fmaxf(sqrtf(ss), 1e-12f);
        ((float4*)(out0 + base))[lane] = v;
        float4 xv; xv.x = v.x*inv; xv.y = v.y*inv; xv.z = v.z*inv; xv.w = v.w*inv;
        ((float4*)(out1 + base))[lane] = xv;
        bf16x4 bv; bv[0]=(__bf16)v.x; bv[1]=(__bf16)v.y; bv[2]=(__bf16)v.z; bv[3]=(__bf16)v.w;
        ((bf16x4*)(Zb + base))[lane] = bv;
        if (lane == 0) { z2[row] = ss; invn[row] = inv; rmin[row] = 0x7f800000u; }
    } else {
        int row  = ((b - (N_ROWS/4)) << 2) + (threadIdx.x >> 6);
        size_t base = (size_t)row * D_DIM;
        float4 v = ((const float4*)(P + base))[lane];
        float ss = v.x*v.x + v.y*v.y + v.z*v.z + v.w*v.w;
        #pragma unroll
        for (int d = 32; d >= 1; d >>= 1) ss += __shfl_xor(ss, d);
        bf16x4 bv; bv[0]=(__bf16)v.x; bv[1]=(__bf16)v.y; bv[2]=(__bf16)v.z; bv[3]=(__bf16)v.w;
        ((bf16x4*)(Pb + base))[lane] = bv;
        if (lane == 0) { p2[row] = ss; cmin[row] = 0x7f800000u; }
    }
}

// ---------------- K3: bf16 MFMA GEMM G = Zb * Pb^T + fused epilogue ----------------
// m97 structure: 128x128 tile, BK=64, global_load_lds width-16 staging, no LDS pad.
// XCD-bijective swizzle (4096 % 8 == 0): all 16 bn-tiles of 32 consecutive bm-strips
// land on one XCD -> per-XCD L2 working set = 2 MB (A) + 1 MB (Pb) < 4 MB.
#define BM 128
#define BN 128
#define BK 64

__global__ __launch_bounds__(256, 2) void k3_gemm(
    const __bf16* __restrict__ Zb, const __bf16* __restrict__ Pb,
    const float* __restrict__ z2, const float* __restrict__ p2,
    const float* __restrict__ invn,
    float* __restrict__ xmap,
    unsigned int* __restrict__ rmin, unsigned int* __restrict__ cmin)
{
    __shared__ __bf16 As[BM * BK];   // 16 KB, rows of 128 B, contiguous
    __shared__ __bf16 Bs[BN * BK];   // 16 KB

    const int tid  = threadIdx.x;
    // XCD swizzle: hw-consecutive-mod-8 blocks (same XCD) -> contiguous logical chunk
    const int wg   = (blockIdx.x & 7) * 512 + (blockIdx.x >> 3);
    const int bn   = wg & 15;   // 16 n-blocks
    const int bm   = wg >> 4;   // 256 m-blocks
    const int lane = tid & 63;
    const int wave = tid >> 6;
    const int wm   = wave >> 1;
    const int wn   = wave & 1;
    const int l15  = lane & 15;
    const int quad = lane >> 4;

    const int m0 = bm * BM;
    const int n0 = bn * BN;

    f32x4 acc[4][4];
    #pragma unroll
    for (int i = 0; i < 4; i++)
        #pragma unroll
        for (int j = 0; j < 4; j++)
            #pragma unroll
            for (int r = 0; r < 4; r++) acc[i][j][r] = 0.0f;

    // staging: chunk = (it*4+wave)*64 + lane (16B units).
    // global src: row = chunk>>3, colchunk = chunk&7 (= lane&7).
    // LDS dst elem offset = chunk*8 -> wave-uniform base (it*4+wave)*512, lane adds lane*16B.
    const int ch_row[4] = {
        ((0*4 + wave)*64 + lane) >> 3, ((1*4 + wave)*64 + lane) >> 3,
        ((2*4 + wave)*64 + lane) >> 3, ((3*4 + wave)*64 + lane) >> 3 };
    const int ch_c = lane & 7;

    for (int kt = 0; kt < D_DIM; kt += BK) {
        #pragma unroll
        for (int it = 0; it < 4; it++) {
            const __bf16* aS = Zb + (size_t)(m0 + ch_row[it]) * D_DIM + kt + ch_c * 8;
            const __bf16* bS = Pb + (size_t)(n0 + ch_row[it]) * D_DIM + kt + ch_c * 8;
            gload16(aS, As + (it*4 + wave) * 512);
            gload16(bS, Bs + (it*4 + wave) * 512);
        }
        __syncthreads();   // drains vmcnt(0): staging visible

        #pragma unroll
        for (int s = 0; s < 2; s++) {
            bf16x8 af[4], bfr[4];
            #pragma unroll
            for (int i = 0; i < 4; i++)
                af[i] = *(const bf16x8*)(As + (wm*64 + i*16 + l15) * BK + s*32 + quad*8);
            #pragma unroll
            for (int j = 0; j < 4; j++)
                bfr[j] = *(const bf16x8*)(Bs + (wn*64 + j*16 + l15) * BK + s*32 + quad*8);
            #pragma unroll
            for (int i = 0; i < 4; i++)
                #pragma unroll
                for (int j = 0; j < 4; j++)
                    acc[i][j] = __builtin_amdgcn_mfma_f32_16x16x32_bf16(af[i], bfr[j], acc[i][j], 0, 0, 0);
        }
        __syncthreads();   // protect LDS before next stage
    }

    // ---- epilogue ----
    // C/D layout (m89-verified): col(n) = lane&15, row(m) = quad*4 + reg
    // Min is taken over SQUARED distances (sqrt is monotone, applied in k4).
    // All minned values clamped >= 0 so uint-bit atomicMin preserves float order.
    float invr[16], zzr[16];
    #pragma unroll
    for (int i = 0; i < 4; i++)
        #pragma unroll
        for (int r = 0; r < 4; r++) {
            int gm = m0 + wm*64 + i*16 + quad*4 + r;
            invr[i*4+r] = invn[gm];
            zzr[i*4+r]  = z2[gm];
        }
    float pp[4];
    #pragma unroll
    for (int j = 0; j < 4; j++) pp[j] = p2[n0 + wn*64 + j*16 + l15];

    float cminv[4] = {3.0e38f, 3.0e38f, 3.0e38f, 3.0e38f};

    #pragma unroll
    for (int i = 0; i < 4; i++) {
        #pragma unroll
        for (int r = 0; r < 4; r++) {
            int gm = m0 + wm*64 + i*16 + quad*4 + r;
            float zi = zzr[i*4+r], iv = invr[i*4+r];
            size_t orow = (size_t)gm * K_PROT + n0 + wn*64 + l15;
            float rv = 3.0e38f;
            #pragma unroll
            for (int j = 0; j < 4; j++) {
                float g = acc[i][j][r];
                xmap[orow + j*16] = g * iv;
                float d2 = fmaxf(zi + pp[j] - 2.0f*g, 0.0f);
                rv = fminf(rv, d2);
                cminv[j] = fminf(cminv[j], d2);
            }
            #pragma unroll
            for (int s = 1; s < 16; s <<= 1) rv = fminf(rv, __shfl_xor(rv, s));
            if (l15 == 0) atomicMin(&rmin[gm], __float_as_uint(rv));
        }
    }
    #pragma unroll
    for (int j = 0; j < 4; j++) {
        float cv = cminv[j];
        cv = fminf(cv, __shfl_xor(cv, 16));
        cv = fminf(cv, __shfl_xor(cv, 32));
        if (quad == 0) atomicMin(&cmin[n0 + wn*64 + j*16 + l15], __float_as_uint(cv));
    }
}

// ---------------- K4: final reductions (sqrt of squared mins) + scalar losses ----------------
__global__ __launch_bounds__(1024) void k4_final(
    const float* __restrict__ rminf, const float* __restrict__ cminf,
    const float* __restrict__ recon, const float* __restrict__ kl,
    const float* __restrict__ mmd, float* __restrict__ out)
{
    __shared__ float sr[16], sc[16];
    int tid = threadIdx.x;
    float a = 0.0f, b = 0.0f;
    for (int i = tid; i < N_ROWS; i += 1024) a += sqrtf(fmaxf(rminf[i], 0.0f));
    for (int i = tid; i < K_PROT; i += 1024) b += sqrtf(fmaxf(cminf[i], 0.0f));
    #pragma unroll
    for (int d = 32; d >= 1; d >>= 1) { a += __shfl_xor(a, d); b += __shfl_xor(b, d); }
    int w = tid >> 6, lane = tid & 63;
    if (lane == 0) { sr[w] = a; sc[w] = b; }
    __syncthreads();
    if (tid == 0) {
        float SA = 0.0f, SB = 0.0f;
        #pragma unroll
        for (int i = 0; i < 16; i++) { SA += sr[i]; SB += sc[i]; }
        out[OUT_CVAE] = recon[0] + 0.5f*kl[0] + mmd[0];
        out[OUT_PROT] = 0.5f*(SA / (float)N_ROWS) + 0.5f*(SB / (float)K_PROT);
    }
}

extern "C" void kernel_launch(void* const* d_in, const int* in_sizes, int n_in,
                              void* d_out, int out_size, void* d_ws, size_t ws_size,
                              hipStream_t stream)
{
    const float* Z     = (const float*)d_in[0];
    const float* P     = (const float*)d_in[1];
    const float* recon = (const float*)d_in[2];
    const float* kl    = (const float*)d_in[3];
    const float* mmd   = (const float*)d_in[4];
    float* out = (float*)d_out;
    float* ws  = (float*)d_ws;

    float* z2   = ws + WS_Z2;
    float* invn = ws + WS_INVN;
    float* p2   = ws + WS_P2;
    unsigned int* rmin = (unsigned int*)(ws + WS_RMIN);
    unsigned int* cmin = (unsigned int*)(ws + WS_CMIN);
    __bf16* Zb = (__bf16*)(ws + WS_ZB);
    __bf16* Pb = (__bf16*)(ws + WS_PB);

    hipLaunchKernelGGL(k12_rows, dim3(N_ROWS/4 + K_PROT/4), dim3(256), 0, stream,
                       Z, P, out + OUT_X0, out + OUT_X1, z2, invn, rmin, Zb, p2, cmin, Pb);
    hipLaunchKernelGGL(k3_gemm, dim3((N_ROWS/BM)*(K_PROT/BN)), dim3(256), 0, stream,
                       Zb, Pb, z2, p2, invn, out + OUT_XMAP, rmin, cmin);
    hipLaunchKernelGGL(k4_final, dim3(1), dim3(1024), 0, stream,
                       (const float*)rmin, (const float*)cmin, recon, kl, mmd, out);
}

// Round 2
// 432.657 us; speedup vs baseline: 1.0107x; 1.0107x over previous
//
#include <hip/hip_runtime.h>
#include <hip/hip_bf16.h>

typedef __bf16 bf16x8 __attribute__((ext_vector_type(8)));
typedef __bf16 bf16x4 __attribute__((ext_vector_type(4)));
typedef float  f32x4  __attribute__((ext_vector_type(4)));

#define N_ROWS 32768
#define D_DIM  256
#define K_PROT 2048

// ws layout (float offsets)
#define WS_Z2    0
#define WS_INVN  32768
#define WS_P2    65536
#define WS_ACC   67584                 // 2 floats (sum of row-mins, sum of col-mins)
#define WS_RP    67600                 // row-min partials [16][32768] f32 = 2 MB
#define WS_CP    (67600 + 524288)      // col-min partials [256][2048] f32 = 2 MB
#define WS_ZB    (67600 + 1048576)     // bf16 Z copy: 32768*256 bf16 (16B-aligned: byte off 4464704)
#define WS_PB    (67600 + 1048576 + 4194304)  // bf16 P copy

// out layout (float offsets)
#define OUT_X0   0UL
#define OUT_X1   8388608UL
#define OUT_XMAP 16777216UL
#define OUT_CVAE 83886080UL
#define OUT_PROT 83886081UL

__device__ __forceinline__ void gload16(const __bf16* gsrc, const __bf16* ldst) {
    auto g = (const __attribute__((address_space(1))) unsigned int*)(unsigned long long)gsrc;
    auto l = (__attribute__((address_space(3))) unsigned int*)(unsigned long long)ldst;
    __builtin_amdgcn_global_load_lds(g, l, 16, 0, 0);
}

// ---------------- K12: fused row prep for Z (norms, copies, bf16) and P (norms, bf16) ----------------
__global__ __launch_bounds__(256) void k12_rows(
    const float* __restrict__ Z, const float* __restrict__ P,
    float* __restrict__ out0, float* __restrict__ out1,
    float* __restrict__ z2, float* __restrict__ invn,
    __bf16* __restrict__ Zb,
    float* __restrict__ p2, __bf16* __restrict__ Pb,
    float* __restrict__ accw)
{
    int b    = blockIdx.x;
    int lane = threadIdx.x & 63;
    if (b == 0 && threadIdx.x < 2) accw[threadIdx.x] = 0.0f;   // init loss accumulators
    if (b < (N_ROWS/4)) {
        int row  = (b << 2) + (threadIdx.x >> 6);
        size_t base = (size_t)row * D_DIM;
        float4 v = ((const float4*)(Z + base))[lane];
        float ss = v.x*v.x + v.y*v.y + v.z*v.z + v.w*v.w;
        #pragma unroll
        for (int d = 32; d >= 1; d >>= 1) ss += __shfl_xor(ss, d);
        float inv = 1.0f / fmaxf(sqrtf(ss), 1e-12f);
        ((float4*)(out0 + base))[lane] = v;
        float4 xv; xv.x = v.x*inv; xv.y = v.y*inv; xv.z = v.z*inv; xv.w = v.w*inv;
        ((float4*)(out1 + base))[lane] = xv;
        bf16x4 bv; bv[0]=(__bf16)v.x; bv[1]=(__bf16)v.y; bv[2]=(__bf16)v.z; bv[3]=(__bf16)v.w;
        ((bf16x4*)(Zb + base))[lane] = bv;
        if (lane == 0) { z2[row] = ss; invn[row] = inv; }
    } else {
        int row  = ((b - (N_ROWS/4)) << 2) + (threadIdx.x >> 6);
        size_t base = (size_t)row * D_DIM;
        float4 v = ((const float4*)(P + base))[lane];
        float ss = v.x*v.x + v.y*v.y + v.z*v.z + v.w*v.w;
        #pragma unroll
        for (int d = 32; d >= 1; d >>= 1) ss += __shfl_xor(ss, d);
        bf16x4 bv; bv[0]=(__bf16)v.x; bv[1]=(__bf16)v.y; bv[2]=(__bf16)v.z; bv[3]=(__bf16)v.w;
        ((bf16x4*)(Pb + base))[lane] = bv;
        if (lane == 0) { p2[row] = ss; }
    }
}

// ---------------- K3: bf16 MFMA GEMM G = Zb * Pb^T + fused epilogue ----------------
// m97 structure: 128x128 tile, BK=64, global_load_lds width-16 staging, no LDS pad.
// (256,3): 3 blocks/CU for cross-block phase diversity (m114) — hides the per-iter
// vmcnt(0) barrier drain that 2 lockstep blocks cannot.
// Epilogue: NO atomics — block-level LDS min-combine, then contiguous partial writes.
#define BM 128
#define BN 128
#define BK 64

__global__ __launch_bounds__(256, 3) void k3_gemm(
    const __bf16* __restrict__ Zb, const __bf16* __restrict__ Pb,
    const float* __restrict__ z2, const float* __restrict__ p2,
    const float* __restrict__ invn,
    float* __restrict__ xmap,
    float* __restrict__ rp, float* __restrict__ cp)
{
    __shared__ __bf16 As[BM * BK];   // 16 KB, rows of 128 B, contiguous
    __shared__ __bf16 Bs[BN * BK];   // 16 KB

    const int tid  = threadIdx.x;
    // XCD swizzle: hw-consecutive-mod-8 blocks (same XCD) -> contiguous logical chunk
    const int wg   = (blockIdx.x & 7) * 512 + (blockIdx.x >> 3);
    const int bn   = wg & 15;   // 16 n-blocks
    const int bm   = wg >> 4;   // 256 m-blocks
    const int lane = tid & 63;
    const int wave = tid >> 6;
    const int wm   = wave >> 1;
    const int wn   = wave & 1;
    const int l15  = lane & 15;
    const int quad = lane >> 4;

    const int m0 = bm * BM;
    const int n0 = bn * BN;

    f32x4 acc[4][4];
    #pragma unroll
    for (int i = 0; i < 4; i++)
        #pragma unroll
        for (int j = 0; j < 4; j++)
            #pragma unroll
            for (int r = 0; r < 4; r++) acc[i][j][r] = 0.0f;

    // staging: chunk = (it*4+wave)*64 + lane (16B units).
    // global src: row = chunk>>3, colchunk = chunk&7 (= lane&7).
    // LDS dst elem offset = chunk*8 -> wave-uniform base (it*4+wave)*512, lane adds lane*16B.
    const int ch_row[4] = {
        ((0*4 + wave)*64 + lane) >> 3, ((1*4 + wave)*64 + lane) >> 3,
        ((2*4 + wave)*64 + lane) >> 3, ((3*4 + wave)*64 + lane) >> 3 };
    const int ch_c = lane & 7;

    for (int kt = 0; kt < D_DIM; kt += BK) {
        #pragma unroll
        for (int it = 0; it < 4; it++) {
            const __bf16* aS = Zb + (size_t)(m0 + ch_row[it]) * D_DIM + kt + ch_c * 8;
            const __bf16* bS = Pb + (size_t)(n0 + ch_row[it]) * D_DIM + kt + ch_c * 8;
            gload16(aS, As + (it*4 + wave) * 512);
            gload16(bS, Bs + (it*4 + wave) * 512);
        }
        __syncthreads();   // drains vmcnt(0): staging visible

        #pragma unroll
        for (int s = 0; s < 2; s++) {
            bf16x8 af[4], bfr[4];
            #pragma unroll
            for (int i = 0; i < 4; i++)
                af[i] = *(const bf16x8*)(As + (wm*64 + i*16 + l15) * BK + s*32 + quad*8);
            #pragma unroll
            for (int j = 0; j < 4; j++)
                bfr[j] = *(const bf16x8*)(Bs + (wn*64 + j*16 + l15) * BK + s*32 + quad*8);
            #pragma unroll
            for (int i = 0; i < 4; i++)
                #pragma unroll
                for (int j = 0; j < 4; j++)
                    acc[i][j] = __builtin_amdgcn_mfma_f32_16x16x32_bf16(af[i], bfr[j], acc[i][j], 0, 0, 0);
        }
        __syncthreads();   // protect LDS before next stage
    }

    // ---- epilogue ----
    // C/D layout (m89-verified): col(n) = lane&15, row(m) = quad*4 + reg
    // Mins over SQUARED distances (sqrt is monotone, applied in k4); all values >= 0.
    float invr[16], zzr[16];
    #pragma unroll
    for (int i = 0; i < 4; i++)
        #pragma unroll
        for (int r = 0; r < 4; r++) {
            int gm = m0 + wm*64 + i*16 + quad*4 + r;
            invr[i*4+r] = invn[gm];
            zzr[i*4+r]  = z2[gm];
        }
    float pp[4];
    #pragma unroll
    for (int j = 0; j < 4; j++) pp[j] = p2[n0 + wn*64 + j*16 + l15];

    float cminv[4] = {3.0e38f, 3.0e38f, 3.0e38f, 3.0e38f};
    float rvv[16];

    #pragma unroll
    for (int i = 0; i < 4; i++) {
        #pragma unroll
        for (int r = 0; r < 4; r++) {
            int gm = m0 + wm*64 + i*16 + quad*4 + r;
            float zi = zzr[i*4+r], iv = invr[i*4+r];
            size_t orow = (size_t)gm * K_PROT + n0 + wn*64 + l15;
            float rv = 3.0e38f;
            #pragma unroll
            for (int j = 0; j < 4; j++) {
                float g = acc[i][j][r];
                xmap[orow + j*16] = g * iv;
                float d2 = fmaxf(zi + pp[j] - 2.0f*g, 0.0f);
                rv = fminf(rv, d2);
                cminv[j] = fminf(cminv[j], d2);
            }
            #pragma unroll
            for (int s = 1; s < 16; s <<= 1) rv = fminf(rv, __shfl_xor(rv, s));
            rvv[i*4+r] = rv;   // valid on all lanes (xor butterfly)
        }
    }
    float cvv[4];
    #pragma unroll
    for (int j = 0; j < 4; j++) {
        float cv = cminv[j];
        cv = fminf(cv, __shfl_xor(cv, 16));
        cv = fminf(cv, __shfl_xor(cv, 32));
        cvv[j] = cv;           // valid on all lanes
    }

    // block-level combine in LDS (As is dead after the K-loop's trailing barrier)
    float* srow = (float*)As;        // 128 row-mins
    float* scol = srow + 128;        // 128 col-mins
    if (wn == 0 && l15 == 0) {
        #pragma unroll
        for (int i = 0; i < 4; i++)
            #pragma unroll
            for (int r = 0; r < 4; r++)
                srow[wm*64 + i*16 + quad*4 + r] = rvv[i*4+r];
    }
    if (wm == 0 && quad == 0) {
        #pragma unroll
        for (int j = 0; j < 4; j++) scol[wn*64 + j*16 + l15] = cvv[j];
    }
    __syncthreads();
    if (wn == 1 && l15 == 0) {
        #pragma unroll
        for (int i = 0; i < 4; i++)
            #pragma unroll
            for (int r = 0; r < 4; r++) {
                int idx = wm*64 + i*16 + quad*4 + r;
                srow[idx] = fminf(srow[idx], rvv[i*4+r]);
            }
    }
    if (wm == 1 && quad == 0) {
        #pragma unroll
        for (int j = 0; j < 4; j++) {
            int c = wn*64 + j*16 + l15;
            scol[c] = fminf(scol[c], cvv[j]);
        }
    }
    __syncthreads();
    if (tid < 128)       rp[(size_t)bn * N_ROWS + m0 + tid] = srow[tid];
    else if (tid < 256)  cp[(size_t)bm * K_PROT + n0 + (tid - 128)] = scol[tid - 128];
}

// ---------------- K4: reduce partials (min over tiles, sqrt, sum) ----------------
// blocks 0..63: rows (512 rows each). blocks 64..79: cols (128 cols each).
__global__ __launch_bounds__(256) void k4_reduce(
    const float* __restrict__ rp, const float* __restrict__ cp,
    float* __restrict__ accw)
{
    __shared__ float sbuf[160];
    int b = blockIdx.x, t = threadIdx.x;
    int lane = t & 63, w = t >> 6;
    if (b < 64) {
        float a = 0.0f;
        #pragma unroll
        for (int rr = 0; rr < 2; rr++) {
            int row = b*512 + rr*256 + t;
            float m = 3.0e38f;
            #pragma unroll
            for (int k = 0; k < 16; k++) m = fminf(m, rp[(size_t)k * N_ROWS + row]);
            a += sqrtf(m);
        }
        #pragma unroll
        for (int d = 32; d >= 1; d >>= 1) a += __shfl_xor(a, d);
        if (lane == 0) sbuf[w] = a;
        __syncthreads();
        if (t == 0) atomicAdd(accw + 0, sbuf[0] + sbuf[1] + sbuf[2] + sbuf[3]);
    } else {
        int col  = (b - 64) * 128 + (t & 127);
        int half = t >> 7;
        float m = 3.0e38f;
        for (int k = half*128; k < half*128 + 128; k++)
            m = fminf(m, cp[(size_t)k * K_PROT + col]);
        if (half == 0) sbuf[t] = m;
        __syncthreads();
        if (half == 1) sbuf[t - 128] = fminf(sbuf[t - 128], m);
        __syncthreads();
        if (t < 128) {
            float s = sqrtf(sbuf[t]);
            #pragma unroll
            for (int d = 32; d >= 1; d >>= 1) s += __shfl_xor(s, d);
            if (lane == 0) sbuf[128 + (t >> 6)] = s;
        }
        __syncthreads();
        if (t == 0) atomicAdd(accw + 1, sbuf[128] + sbuf[129]);
    }
}

// ---------------- K5: finalize scalar outputs ----------------
__global__ void k5_final(
    const float* __restrict__ accw,
    const float* __restrict__ recon, const float* __restrict__ kl,
    const float* __restrict__ mmd, float* __restrict__ out)
{
    out[OUT_CVAE] = recon[0] + 0.5f*kl[0] + mmd[0];
    out[OUT_PROT] = 0.5f*(accw[0] / (float)N_ROWS) + 0.5f*(accw[1] / (float)K_PROT);
}

extern "C" void kernel_launch(void* const* d_in, const int* in_sizes, int n_in,
                              void* d_out, int out_size, void* d_ws, size_t ws_size,
                              hipStream_t stream)
{
    const float* Z     = (const float*)d_in[0];
    const float* P     = (const float*)d_in[1];
    const float* recon = (const float*)d_in[2];
    const float* kl    = (const float*)d_in[3];
    const float* mmd   = (const float*)d_in[4];
    float* out = (float*)d_out;
    float* ws  = (float*)d_ws;

    float* z2   = ws + WS_Z2;
    float* invn = ws + WS_INVN;
    float* p2   = ws + WS_P2;
    float* accw = ws + WS_ACC;
    float* rp   = ws + WS_RP;
    float* cp   = ws + WS_CP;
    __bf16* Zb = (__bf16*)(ws + WS_ZB);
    __bf16* Pb = (__bf16*)(ws + WS_PB);

    hipLaunchKernelGGL(k12_rows, dim3(N_ROWS/4 + K_PROT/4), dim3(256), 0, stream,
                       Z, P, out + OUT_X0, out + OUT_X1, z2, invn, Zb, p2, Pb, accw);
    hipLaunchKernelGGL(k3_gemm, dim3((N_ROWS/BM)*(K_PROT/BN)), dim3(256), 0, stream,
                       Zb, Pb, z2, p2, invn, out + OUT_XMAP, rp, cp);
    hipLaunchKernelGGL(k4_reduce, dim3(80), dim3(256), 0, stream, rp, cp, accw);
    hipLaunchKernelGGL(k5_final, dim3(1), dim3(1), 0, stream, accw, recon, kl, mmd, out);
}